// Round 3
// baseline (140.007 us; speedup 1.0000x reference)
//
#include <hip/hip_runtime.h>

// SSD MultiBoxLoss: B=64, P=29126, G=24, 2 classes, scalar fp32 output.
static constexpr int B_ = 64;
static constexpr int P_ = 29126;
static constexpr int G_ = 24;
static constexpr float THRESH_ = 0.35f;
static constexpr int NEGPOS_ = 7;
static constexpr int PB_ = (P_ + 255) / 256;   // 114 p-blocks for k_loss
static constexpr int NBLK_ = PB_ * B_;         // 7296 partial slots

__device__ inline unsigned long long shflxor64(unsigned long long v, int m) {
    unsigned int lo = (unsigned int)v, hi = (unsigned int)(v >> 32);
    lo = __shfl_xor(lo, m, 64);
    hi = __shfl_xor(hi, m, 64);
    return ((unsigned long long)hi << 32) | lo;
}

// ---------------------------------------------------------------- kernel 1
// Per-(b,g) best prior: pk = (iou_bits<<32) | ~p; max => best iou, tie => min p.
// grid: (8 p-groups, 3 g-groups, B), 256 threads. 8 packed maxima per thread.
__global__ __launch_bounds__(256) void k_best_prior(
    const float4* __restrict__ gt4,      // [B*G] point-form
    const float4* __restrict__ priors4,  // [P] (cx,cy,w,h)
    unsigned long long* __restrict__ bp_pack)   // [B*G], zeroed
{
    const int tid = threadIdx.x;
    const int b = blockIdx.z;
    const int g0 = blockIdx.y * 8;
    __shared__ float4 sgt[8];
    __shared__ float  sarea[8];
    __shared__ unsigned long long swv[4][8];
    if (tid < 8) {
        const float4 t = gt4[b*G_ + g0 + tid];
        sgt[tid] = t;
        sarea[tid] = (t.z - t.x) * (t.w - t.y);
    }
    __syncthreads();

    unsigned long long best[8];
#pragma unroll
    for (int j = 0; j < 8; ++j) best[j] = 0ull;

    for (int p = blockIdx.x*256 + tid; p < P_; p += 2048) {
        const float4 pr = priors4[p];
        const float hx = pr.z * 0.5f, hy = pr.w * 0.5f;
        const float px0 = pr.x - hx, py0 = pr.y - hy;
        const float px1 = pr.x + hx, py1 = pr.y + hy;
        const float area_p = (px1 - px0) * (py1 - py0);
        const unsigned long long plow = (unsigned long long)(~(unsigned int)p);
#pragma unroll
        for (int j = 0; j < 8; ++j) {
            const float4 t = sgt[j];
            const float lx = fmaxf(t.x, px0), ly = fmaxf(t.y, py0);
            const float rx = fminf(t.z, px1), ry = fminf(t.w, py1);
            const float iw = fmaxf(rx - lx, 0.0f), ih = fmaxf(ry - ly, 0.0f);
            const float inter = iw * ih;
            const float iou = __fdividef(inter, (sarea[j] + area_p) - inter);
            const unsigned long long pk =
                ((unsigned long long)__float_as_uint(iou) << 32) | plow;
            if (pk > best[j]) best[j] = pk;
        }
    }

    const int lane = tid & 63, wave = tid >> 6;
#pragma unroll
    for (int j = 0; j < 8; ++j) {
        unsigned long long v = best[j];
        for (int m = 32; m; m >>= 1) {
            const unsigned long long o = shflxor64(v, m);
            if (o > v) v = o;
        }
        if (lane == 0) swv[wave][j] = v;
    }
    __syncthreads();
    if (tid < 8) {
        unsigned long long m = swv[0][tid];
        if (swv[1][tid] > m) m = swv[1][tid];
        if (swv[2][tid] > m) m = swv[2][tid];
        if (swv[3][tid] > m) m = swv[3][tid];
        atomicMax(&bp_pack[b*G_ + g0 + tid], m);
    }
}

// ---------------------------------------------------------------- kernel 2
// Fused per-(b,p): 24-way IoU argmax (first occurrence), inline override
// (last-g-wins), CE, smooth-L1 on positives, mine write, per-block partials.
__global__ __launch_bounds__(256) void k_loss(
    const float4* __restrict__ loc4,   // [B*P]
    const float2* __restrict__ conf2,  // [B*P]
    const float4* __restrict__ gt4,    // [B*G]
    const int* __restrict__ labels,    // [B*G]
    const float4* __restrict__ priors4,
    const unsigned long long* __restrict__ bp_pack,
    float* __restrict__ mine,          // [B*P]
    float* __restrict__ pl, float* __restrict__ pc, int* __restrict__ pp)
{
    const int b = blockIdx.y;
    const int tid = threadIdx.x;
    __shared__ float4 sgt[G_];
    __shared__ float  sarea[G_];
    __shared__ int    sbpi[G_];
    __shared__ int    slab[G_];
    if (tid < G_) {
        const float4 t = gt4[b*G_ + tid];
        sgt[tid] = t;
        sarea[tid] = (t.z - t.x) * (t.w - t.y);
        sbpi[tid] = (int)(~(unsigned int)(bp_pack[b*G_ + tid] & 0xFFFFFFFFull));
        slab[tid] = labels[b*G_ + tid];
    }
    __syncthreads();

    const int p = blockIdx.x*256 + tid;
    float lL = 0.0f, pce = 0.0f; int np = 0;
    if (p < P_) {
        const int idx = b*P_ + p;
        const float4 pr = priors4[p];
        const float hx = pr.z * 0.5f, hy = pr.w * 0.5f;
        const float px0 = pr.x - hx, py0 = pr.y - hy;
        const float px1 = pr.x + hx, py1 = pr.y + hy;
        const float area_p = (px1 - px0) * (py1 - py0);

        float bv = -1.0f; int bg = 0;
#pragma unroll
        for (int g = 0; g < G_; ++g) {
            const float4 t = sgt[g];
            const float lx = fmaxf(t.x, px0), ly = fmaxf(t.y, py0);
            const float rx = fminf(t.z, px1), ry = fminf(t.w, py1);
            const float iw = fmaxf(rx - lx, 0.0f), ih = fmaxf(ry - ly, 0.0f);
            const float inter = iw * ih;
            const float iou = __fdividef(inter, (sarea[g] + area_p) - inter);
            if (iou > bv) { bv = iou; bg = g; }       // strict > => first g
        }
        int og = -1;
#pragma unroll
        for (int g = 0; g < G_; ++g)
            if (sbpi[g] == p) og = g;                 // ascending => last wins
        if (og >= 0) { bv = 2.0f; bg = og; }

        const int cc = (bv < THRESH_) ? 0 : slab[bg];

        const float2 x = conf2[idx];
        const float mx = fmaxf(x.x, x.y);
        const float lse = mx + logf(expf(x.x - mx) + expf(x.y - mx));
        const float ce = lse - ((cc == 0) ? x.x : x.y);

        float mv = ce;
        if (cc > 0) {
            np = 1; pce = ce; mv = 0.0f;
            const float4 t = sgt[bg];
            const float gcx = ((t.x + t.z)*0.5f - pr.x) / (0.1f*pr.z);
            const float gcy = ((t.y + t.w)*0.5f - pr.y) / (0.1f*pr.w);
            const float gw  = logf((t.z - t.x)/pr.z) / 0.2f;
            const float gh  = logf((t.w - t.y)/pr.w) / 0.2f;
            const float4 l = loc4[idx];
            const float d0 = fabsf(l.x - gcx);
            const float d1 = fabsf(l.y - gcy);
            const float d2 = fabsf(l.z - gw);
            const float d3 = fabsf(l.w - gh);
            lL  = (d0 < 1.0f) ? 0.5f*d0*d0 : d0 - 0.5f;
            lL += (d1 < 1.0f) ? 0.5f*d1*d1 : d1 - 0.5f;
            lL += (d2 < 1.0f) ? 0.5f*d2*d2 : d2 - 0.5f;
            lL += (d3 < 1.0f) ? 0.5f*d3*d3 : d3 - 0.5f;
        }
        mine[idx] = mv;
    }

    __shared__ float sL[256], sC[256];
    __shared__ int   sP[256];
    sL[tid] = lL; sC[tid] = pce; sP[tid] = np;
    __syncthreads();
    for (int off = 128; off > 0; off >>= 1) {
        if (tid < off) {
            sL[tid] += sL[tid+off];
            sC[tid] += sC[tid+off];
            sP[tid] += sP[tid+off];
        }
        __syncthreads();
    }
    if (tid == 0) {
        const int o = b*PB_ + blockIdx.x;
        pl[o] = sL[0]; pc[o] = sC[0]; pp[o] = sP[0];
    }
}

// ---------------------------------------------------------------- kernel 3
// Per batch: top-k sum of mine, k = min(7*num_pos, P-1). num_pos computed
// from pp partials in-block. 4-pass radix select, per-wave histograms.
__global__ __launch_bounds__(1024) void k_topk(
    const float* __restrict__ mine, const int* __restrict__ pp,
    float* __restrict__ ctop)
{
    const int b = blockIdx.x;
    const int tid = threadIdx.x;
    const int wave = tid >> 6;

    __shared__ int swnp[16];
    __shared__ int snp;
    int v = (tid < PB_) ? pp[b*PB_ + tid] : 0;
    for (int m = 32; m; m >>= 1) v += __shfl_xor(v, m, 64);
    if ((tid & 63) == 0) swnp[wave] = v;
    __syncthreads();
    if (tid == 0) {
        int s = 0;
#pragma unroll
        for (int w = 0; w < 16; ++w) s += swnp[w];
        snp = s;
    }
    __syncthreads();
    const int np = snp;
    int k = NEGPOS_ * np; if (k > P_-1) k = P_-1;
    if (k <= 0) { if (tid == 0) ctop[b] = 0.0f; return; }   // block-uniform

    const float* row = mine + (size_t)b * P_;
    __shared__ unsigned int hist[16*256];
    __shared__ unsigned int sc0[256], sc1[256];
    __shared__ unsigned int sh_prefix;
    __shared__ int sh_kk;

    unsigned int prefix = 0; int kk = k;
    for (int pass = 3; pass >= 0; --pass) {
        for (int i = tid; i < 16*256; i += 1024) hist[i] = 0;
        __syncthreads();
        const unsigned int highmask =
            (pass == 3) ? 0u : (0xFFFFFFFFu << ((pass+1)*8));
        for (int p = tid; p < P_; p += 1024) {
            const unsigned int u = __float_as_uint(row[p]);
            if ((u & highmask) == (prefix & highmask))
                atomicAdd(&hist[wave*256 + ((u >> (pass*8)) & 255u)], 1u);
        }
        __syncthreads();
        if (tid < 256) {
            unsigned int m = 0;
#pragma unroll
            for (int w = 0; w < 16; ++w) m += hist[w*256 + (255 - tid)];
            sc0[tid] = m;                       // count(bin == 255-tid)
        }
        __syncthreads();
        unsigned int* src = sc0; unsigned int* dst = sc1;
        for (int off = 1; off < 256; off <<= 1) {
            if (tid < 256) {
                unsigned int x = src[tid];
                if (tid >= off) x += src[tid - off];
                dst[tid] = x;
            }
            __syncthreads();
            unsigned int* t = src; src = dst; dst = t;
        }
        if (tid < 256) {
            const int bin = 255 - tid;
            const int cum = (int)src[tid];
            const int cumPrev = (tid == 0) ? 0 : (int)src[tid-1]; // bins > bin
            if (cum >= kk && cumPrev < kk) {     // exactly one thread
                sh_prefix = prefix | ((unsigned int)bin << (pass*8));
                sh_kk = kk - cumPrev;
            }
        }
        __syncthreads();
        prefix = sh_prefix; kk = sh_kk;
        __syncthreads();
    }

    const float T = __uint_as_float(prefix);
    float sum = 0.0f; int cnt = 0;
    for (int p = tid; p < P_; p += 1024) {
        const float x = row[p];
        if (x > T) { sum += x; ++cnt; }
    }
    for (int m = 32; m; m >>= 1) {
        sum += __shfl_xor(sum, m, 64);
        cnt += __shfl_xor(cnt, m, 64);
    }
    __shared__ float wsum[16];
    __shared__ int   wcnt[16];
    if ((tid & 63) == 0) { wsum[wave] = sum; wcnt[wave] = cnt; }
    __syncthreads();
    if (tid == 0) {
        float s = 0.0f; int c2 = 0;
#pragma unroll
        for (int w = 0; w < 16; ++w) { s += wsum[w]; c2 += wcnt[w]; }
        ctop[b] = s + (float)(k - c2) * T;       // ties at threshold
    }
}

// ---------------------------------------------------------------- kernel 4
// Global reduction of all partials + ctop -> scalar loss.
__global__ __launch_bounds__(256) void k_final(
    const float* __restrict__ pl, const float* __restrict__ pc,
    const int* __restrict__ pp, const float* __restrict__ ctop,
    float* __restrict__ out)
{
    const int tid = threadIdx.x;
    float sL = 0.0f, sC = 0.0f; int tp = 0;
    for (int i = tid; i < NBLK_; i += 256) {
        sL += pl[i]; sC += pc[i]; tp += pp[i];
    }
    float sT = (tid < B_) ? ctop[tid] : 0.0f;
    __shared__ float aL[256], aC[256], aT[256];
    __shared__ int   aP[256];
    aL[tid] = sL; aC[tid] = sC; aT[tid] = sT; aP[tid] = tp;
    __syncthreads();
    for (int off = 128; off > 0; off >>= 1) {
        if (tid < off) {
            aL[tid] += aL[tid+off];
            aC[tid] += aC[tid+off];
            aT[tid] += aT[tid+off];
            aP[tid] += aP[tid+off];
        }
        __syncthreads();
    }
    if (tid == 0) {
        const float N = fmaxf((float)aP[0], 1.0f);
        out[0] = (2.0f*aL[0] + aC[0] + aT[0]) / N;
    }
}

// ----------------------------------------------------------------
extern "C" void kernel_launch(void* const* d_in, const int* in_sizes, int n_in,
                              void* d_out, int out_size, void* d_ws, size_t ws_size,
                              hipStream_t stream)
{
    const float* loc    = (const float*)d_in[0];   // [B,P,4]
    const float* conf   = (const float*)d_in[1];   // [B,P,2]
    const float* gt     = (const float*)d_in[2];   // [B,G,4]
    const int*   labels = (const int*)d_in[3];     // [B,G]
    const float* priors = (const float*)d_in[4];   // [P,4]
    float* out = (float*)d_out;

    char* ws = (char*)d_ws;
    size_t off = 0;
    float* mine = (float*)(ws + off);                off += (size_t)B_*P_*4;
    unsigned long long* bp_pack =
        (unsigned long long*)(ws + off);             off += (size_t)B_*G_*8;
    float* pl = (float*)(ws + off);                  off += (size_t)NBLK_*4;
    float* pc = (float*)(ws + off);                  off += (size_t)NBLK_*4;
    int*   pp = (int*)(ws + off);                    off += (size_t)NBLK_*4;
    float* ctop = (float*)(ws + off);                off += (size_t)B_*4;

    hipMemsetAsync(bp_pack, 0, (size_t)B_*G_*8, stream);

    k_best_prior<<<dim3(8, 3, B_), dim3(256), 0, stream>>>(
        (const float4*)gt, (const float4*)priors, bp_pack);
    k_loss<<<dim3(PB_, B_), dim3(256), 0, stream>>>(
        (const float4*)loc, (const float2*)conf, (const float4*)gt, labels,
        (const float4*)priors, bp_pack, mine, pl, pc, pp);
    k_topk<<<dim3(B_), dim3(1024), 0, stream>>>(mine, pp, ctop);
    k_final<<<dim3(1), dim3(256), 0, stream>>>(pl, pc, pp, ctop, out);
}